// Round 6
// baseline (731.782 us; speedup 1.0000x reference)
//
#include <hip/hip_runtime.h>
#include <math.h>

#define D_IN 64
#define D_H 40
#define D_OUT 24

typedef unsigned int u32;
typedef unsigned short u16;

// ---------------- CSR build ----------------
__global__ void hist_rank(const int* __restrict__ dst, int* __restrict__ deg,
                          int* __restrict__ rank, int E) {
    int i = blockIdx.x * blockDim.x + threadIdx.x;
    int b = i * 4;
    if (b + 3 < E) {
        int4 d = ((const int4*)dst)[i];
        int4 r;
        r.x = atomicAdd(&deg[d.x], 1);
        r.y = atomicAdd(&deg[d.y], 1);
        r.z = atomicAdd(&deg[d.z], 1);
        r.w = atomicAdd(&deg[d.w], 1);
        ((int4*)rank)[i] = r;
    } else {
        for (int k = b; k < E; ++k) rank[k] = atomicAdd(&deg[dst[k]], 1);
    }
}

__global__ void scan_blocks(const int* __restrict__ deg, int* __restrict__ off,
                            int* __restrict__ bsum, int n) {
    __shared__ int s[256];
    int tx = threadIdx.x;
    int i = blockIdx.x * 256 + tx;
    int v = (i < n) ? deg[i] : 0;
    s[tx] = v;
    __syncthreads();
    for (int d = 1; d < 256; d <<= 1) {
        int t = (tx >= d) ? s[tx - d] : 0;
        __syncthreads();
        s[tx] += t;
        __syncthreads();
    }
    if (i < n) off[i] = s[tx] - v;
    if (tx == 255) bsum[blockIdx.x] = s[255];
}

__global__ void scan_tops(int* __restrict__ bsum, int nb, int* __restrict__ off, int n) {
    int lane = threadIdx.x & 63;
    int carry = 0;
    for (int base = 0; base < nb; base += 64) {
        int i = base + lane;
        int orig = (i < nb) ? bsum[i] : 0;
        int v = orig;
        #pragma unroll
        for (int d = 1; d < 64; d <<= 1) {
            int t = __shfl_up(v, d);
            if (lane >= d) v += t;
        }
        if (i < nb) bsum[i] = carry + v - orig;
        carry += __shfl(v, 63);
    }
    if (lane == 0) off[n] = carry;
}

__global__ void add_offsets(int* __restrict__ off, const int* __restrict__ bsum, int n) {
    int i = blockIdx.x * blockDim.x + threadIdx.x;
    if (i < n) off[i] += bsum[i >> 8];
}

__global__ void placement(const int* __restrict__ src, const int* __restrict__ dst,
                          const int* __restrict__ rank, const int* __restrict__ off,
                          int* __restrict__ csr, int E) {
    int i = blockIdx.x * blockDim.x + threadIdx.x;
    int b = i * 4;
    if (b + 3 < E) {
        int4 s = ((const int4*)src)[i];
        int4 d = ((const int4*)dst)[i];
        int4 r = ((const int4*)rank)[i];
        csr[off[d.x] + r.x] = s.x;
        csr[off[d.y] + r.y] = s.y;
        csr[off[d.z] + r.z] = s.z;
        csr[off[d.w] + r.w] = s.w;
    } else {
        for (int k = b; k < E; ++k) csr[off[dst[k]] + rank[k]] = src[k];
    }
}

// ---------------- bf16 helpers ----------------
__device__ inline u16 f32_to_bf16_rne(float f) {
    u32 u = __float_as_uint(f);
    u += 0x7fffu + ((u >> 16) & 1u);
    return (u16)(u >> 16);
}

__device__ inline void accum8(float* a, uint4 w) {
    a[0] += __uint_as_float(w.x << 16);
    a[1] += __uint_as_float(w.x & 0xffff0000u);
    a[2] += __uint_as_float(w.y << 16);
    a[3] += __uint_as_float(w.y & 0xffff0000u);
    a[4] += __uint_as_float(w.z << 16);
    a[5] += __uint_as_float(w.z & 0xffff0000u);
    a[6] += __uint_as_float(w.w << 16);
    a[7] += __uint_as_float(w.w & 0xffff0000u);
}

// ---------------- pre1: xl = bf16(x@W1l^T), xr = x@W1r^T + b1 ----------------
__global__ void pre1(const float* __restrict__ x, const float* __restrict__ W1l,
                     const float* __restrict__ W1r, const float* __restrict__ b1,
                     u16* __restrict__ xl, float* __restrict__ xr, int n) {
    __shared__ __align__(16) float xs[4][D_IN];
    int local = threadIdx.x >> 6;
    int lane  = threadIdx.x & 63;
    int node  = blockIdx.x * 4 + local;
    if (node < n) xs[local][lane] = x[(size_t)node * D_IN + lane];
    __syncthreads();
    if (node < n && lane < D_H) {
        const float4* wl = (const float4*)(W1l + lane * D_IN);
        const float4* wr = (const float4*)(W1r + lane * D_IN);
        const float4* v  = (const float4*)xs[local];
        float al = 0.0f, ar = 0.0f;
        #pragma unroll
        for (int k = 0; k < D_IN / 4; ++k) {
            float4 a = wl[k], c = wr[k], b = v[k];
            al += a.x * b.x + a.y * b.y + a.z * b.z + a.w * b.w;
            ar += c.x * b.x + c.y * b.y + c.z * b.z + c.w * b.w;
        }
        xl[(size_t)node * D_H + lane] = f32_to_bf16_rne(al);
        xr[(size_t)node * D_H + lane] = ar + b1[lane];
    }
}

// ---------------- Layer 1: h = relu(mean_gather(xl) + xr), in-place on xr ----
// 12 groups x 5 lanes, 4-way unrolled: 48 neighbor rows per iteration.
__global__ void gather_node1(const u32* __restrict__ xlp,
                             const int* __restrict__ off,
                             const int* __restrict__ csr,
                             float* __restrict__ hbuf,  // xr in, h out (n x 40)
                             int n) {
    __shared__ __align__(16) float part[4][12][D_H];
    int local = threadIdx.x >> 6;
    int lane  = threadIdx.x & 63;
    int node  = blockIdx.x * 4 + local;
    int g = lane / 5;          // 0..12 (lanes 60..63 idle in gather)
    int t = lane - g * 5;      // 0..4
    int deg = 0;
    const uint4* rows = (const uint4*)xlp;   // 5 uint4 per row
    if (node < n) {
        int o0 = off[node], o1 = off[node + 1];
        deg = o1 - o0;
        float a0[8] = {0,0,0,0,0,0,0,0};
        float a1[8] = {0,0,0,0,0,0,0,0};
        float a2[8] = {0,0,0,0,0,0,0,0};
        float a3[8] = {0,0,0,0,0,0,0,0};
        for (int base = o0; base < o1; base += 64) {
            int cnt = min(64, o1 - base);
            int idx = (base + lane < o1) ? csr[base + lane] : 0;
            if (g < 12) {
                for (int j = 0; j < cnt; j += 48) {
                    int j0 = j + g, j1 = j + 12 + g, j2 = j + 24 + g, j3 = j + 36 + g;
                    int s0 = __shfl(idx, j0 & 63);
                    int s1 = __shfl(idx, j1 & 63);
                    int s2 = __shfl(idx, j2 & 63);
                    int s3 = __shfl(idx, j3 & 63);
                    uint4 w0 = rows[(size_t)s0 * 5 + t];
                    uint4 w1 = rows[(size_t)s1 * 5 + t];
                    uint4 w2 = rows[(size_t)s2 * 5 + t];
                    uint4 w3 = rows[(size_t)s3 * 5 + t];
                    if (j0 < cnt) accum8(a0, w0);
                    if (j1 < cnt) accum8(a1, w1);
                    if (j2 < cnt) accum8(a2, w2);
                    if (j3 < cnt) accum8(a3, w3);
                }
            }
        }
        if (g < 12) {
            #pragma unroll
            for (int k = 0; k < 8; ++k) a0[k] += a1[k] + a2[k] + a3[k];
            float* p = &part[local][g][t * 8];
            ((float4*)p)[0] = make_float4(a0[0], a0[1], a0[2], a0[3]);
            ((float4*)p)[1] = make_float4(a0[4], a0[5], a0[6], a0[7]);
        }
    }
    __syncthreads();
    if (node < n && lane < D_H) {
        float inv = 1.0f / fmaxf((float)deg, 1.0f);
        float agg = 0.0f;
        #pragma unroll
        for (int gg = 0; gg < 12; ++gg) agg += part[local][gg][lane];
        size_t p = (size_t)node * D_H + lane;
        hbuf[p] = fmaxf(agg * inv + hbuf[p], 0.0f);
    }
}

// ---------------- pre2: h2 = bf16(h@W2l^T) compact; hr = h@W2r^T + b2 --------
// hr written in-place into the h row (first 24 floats) — h dead afterwards.
__global__ void pre2(float* __restrict__ hbuf, const float* __restrict__ W2l,
                     const float* __restrict__ W2r, const float* __restrict__ b2,
                     u16* __restrict__ h2, int n) {
    __shared__ __align__(16) float hs[4][D_H];
    int local = threadIdx.x >> 6;
    int lane  = threadIdx.x & 63;
    int node  = blockIdx.x * 4 + local;
    if (node < n && lane < D_H) hs[local][lane] = hbuf[(size_t)node * D_H + lane];
    __syncthreads();
    if (node < n && lane < D_OUT) {
        const float4* w = (const float4*)(W2l + lane * D_H);
        const float4* v = (const float4*)hs[local];
        float acc = 0.0f;
        #pragma unroll
        for (int k = 0; k < D_H / 4; ++k) {
            float4 a = w[k], b = v[k];
            acc += a.x * b.x + a.y * b.y + a.z * b.z + a.w * b.w;
        }
        h2[(size_t)node * D_OUT + lane] = f32_to_bf16_rne(acc);
    }
    if (node < n && lane >= 32 && lane < 32 + D_OUT) {
        int k2 = lane - 32;
        const float4* w = (const float4*)(W2r + k2 * D_H);
        const float4* v = (const float4*)hs[local];
        float acc = 0.0f;
        #pragma unroll
        for (int k = 0; k < D_H / 4; ++k) {
            float4 a = w[k], b = v[k];
            acc += a.x * b.x + a.y * b.y + a.z * b.z + a.w * b.w;
        }
        hbuf[(size_t)node * D_H + k2] = acc + b2[k2];
    }
}

// ---------------- Layer 2: out = log_softmax(mean_gather(h2) + hr) -----------
// 21 groups x 3 lanes; 48B compact rows; 2x unroll (42 rows/iter).
__global__ void gather_node2(const u32* __restrict__ h2p,
                             const int* __restrict__ off,
                             const int* __restrict__ csr,
                             const float* __restrict__ hbuf,  // hr rows (stride 40)
                             float* __restrict__ out, int n) {
    __shared__ __align__(16) float part[4][21][D_OUT];
    __shared__ float os[4][D_OUT];
    int local = threadIdx.x >> 6;
    int lane  = threadIdx.x & 63;
    int node  = blockIdx.x * 4 + local;
    int g = lane / 3;          // 0..21 (lane 63 idle in gather)
    int t = lane - g * 3;      // 0..2
    int deg = 0;
    const uint4* rows = (const uint4*)h2p;   // 3 uint4 per row
    if (node < n) {
        int o0 = off[node], o1 = off[node + 1];
        deg = o1 - o0;
        float a0[8] = {0,0,0,0,0,0,0,0};
        float a1[8] = {0,0,0,0,0,0,0,0};
        for (int base = o0; base < o1; base += 64) {
            int cnt = min(64, o1 - base);
            int idx = (base + lane < o1) ? csr[base + lane] : 0;
            if (g < 21) {
                for (int j = 0; j < cnt; j += 42) {
                    int j0 = j + g, j1 = j + 21 + g;
                    int s0 = __shfl(idx, j0 & 63);
                    int s1 = __shfl(idx, j1 & 63);
                    uint4 w0 = rows[(size_t)s0 * 3 + t];
                    uint4 w1 = rows[(size_t)s1 * 3 + t];
                    if (j0 < cnt) accum8(a0, w0);
                    if (j1 < cnt) accum8(a1, w1);
                }
            }
        }
        if (g < 21) {
            #pragma unroll
            for (int k = 0; k < 8; ++k) a0[k] += a1[k];
            float* p = &part[local][g][t * 8];
            ((float4*)p)[0] = make_float4(a0[0], a0[1], a0[2], a0[3]);
            ((float4*)p)[1] = make_float4(a0[4], a0[5], a0[6], a0[7]);
        }
    }
    __syncthreads();
    if (node < n && lane < D_OUT) {
        float inv = 1.0f / fmaxf((float)deg, 1.0f);
        float agg = 0.0f;
        #pragma unroll
        for (int gg = 0; gg < 21; ++gg) agg += part[local][gg][lane];
        os[local][lane] = agg * inv + hbuf[(size_t)node * D_H + lane];
    }
    __syncthreads();
    if (node < n && lane < D_OUT) {
        float m = -INFINITY;
        #pragma unroll
        for (int k = 0; k < D_OUT; ++k) m = fmaxf(m, os[local][k]);
        float se = 0.0f;
        #pragma unroll
        for (int k = 0; k < D_OUT; ++k) se += expf(os[local][k] - m);
        out[(size_t)node * D_OUT + lane] = os[local][lane] - m - logf(se);
    }
}

extern "C" void kernel_launch(void* const* d_in, const int* in_sizes, int n_in,
                              void* d_out, int out_size, void* d_ws, size_t ws_size,
                              hipStream_t stream) {
    const float* x   = (const float*)d_in[0];
    const int*   ei  = (const int*)d_in[1];
    const float* W1l = (const float*)d_in[2];
    const float* b1  = (const float*)d_in[3];
    const float* W1r = (const float*)d_in[4];
    const float* W2l = (const float*)d_in[5];
    const float* b2  = (const float*)d_in[6];
    const float* W2r = (const float*)d_in[7];
    float* out = (float*)d_out;

    const int n = in_sizes[0] / D_IN;      // 100000
    const int E = in_sizes[1] / 2;         // 3200000
    const int* src = ei;
    const int* dst = ei + E;
    const int nb = (n + 255) / 256;

    // Workspace (~37.6 MB):
    //  buf0: n*40 f32 = 16 MB  — lifetimes: rank -> xr -> h -> hr (in-place)
    //  xl  : n*40 bf16 = 8 MB  — lifetimes: xl -> h2 (compact n*24 bf16)
    //  off/deg/bsum, csr (12.8 MB)
    char* ws = (char*)d_ws;
    float* buf0 = (float*)ws;
    int*   rank = (int*)ws;          ws += (size_t)n * D_H * 4;
    u16*   xl   = (u16*)ws;
    u16*   h2   = (u16*)ws;          ws += (size_t)n * D_H * 2;
    int*   off  = (int*)ws;          ws += (((size_t)(n + 1) * 4 + 15) & ~15ull);
    int*   deg  = (int*)ws;          ws += (size_t)n * 4;
    int*   bsum = (int*)ws;          ws += (((size_t)nb * 4 + 15) & ~15ull);
    int*   csr  = (int*)ws;

    hipMemsetAsync(deg, 0, (size_t)n * 4, stream);

    const int E4 = (E + 3) / 4;
    hist_rank<<<(E4 + 255) / 256, 256, 0, stream>>>(dst, deg, rank, E);
    scan_blocks<<<nb, 256, 0, stream>>>(deg, off, bsum, n);
    scan_tops<<<1, 64, 0, stream>>>(bsum, nb, off, n);
    add_offsets<<<(n + 255) / 256, 256, 0, stream>>>(off, bsum, n);
    placement<<<(E4 + 255) / 256, 256, 0, stream>>>(src, dst, rank, off, csr, E);

    pre1<<<(n + 3) / 4, 256, 0, stream>>>(x, W1l, W1r, b1, xl, buf0, n);
    gather_node1<<<(n + 3) / 4, 256, 0, stream>>>((const u32*)xl, off, csr, buf0, n);
    pre2<<<(n + 3) / 4, 256, 0, stream>>>(buf0, W2l, W2r, b2, h2, n);
    gather_node2<<<(n + 3) / 4, 256, 0, stream>>>((const u32*)h2, off, csr, buf0, out, n);
}

// Round 7
// 501.993 us; speedup vs baseline: 1.4578x; 1.4578x over previous
//
#include <hip/hip_runtime.h>
#include <math.h>

#define D_IN 64
#define D_H 40
#define D_OUT 24

typedef unsigned int u32;
typedef unsigned short u16;

// ---------------- CSR build ----------------
__global__ void hist_rank(const int* __restrict__ dst, int* __restrict__ deg,
                          int* __restrict__ rank, int E) {
    int i = blockIdx.x * blockDim.x + threadIdx.x;
    int b = i * 4;
    if (b + 3 < E) {
        int4 d = ((const int4*)dst)[i];
        int4 r;
        r.x = atomicAdd(&deg[d.x], 1);
        r.y = atomicAdd(&deg[d.y], 1);
        r.z = atomicAdd(&deg[d.z], 1);
        r.w = atomicAdd(&deg[d.w], 1);
        ((int4*)rank)[i] = r;
    } else {
        for (int k = b; k < E; ++k) rank[k] = atomicAdd(&deg[dst[k]], 1);
    }
}

__global__ void scan_blocks(const int* __restrict__ deg, int* __restrict__ off,
                            int* __restrict__ bsum, int n) {
    __shared__ int s[256];
    int tx = threadIdx.x;
    int i = blockIdx.x * 256 + tx;
    int v = (i < n) ? deg[i] : 0;
    s[tx] = v;
    __syncthreads();
    for (int d = 1; d < 256; d <<= 1) {
        int t = (tx >= d) ? s[tx - d] : 0;
        __syncthreads();
        s[tx] += t;
        __syncthreads();
    }
    if (i < n) off[i] = s[tx] - v;
    if (tx == 255) bsum[blockIdx.x] = s[255];
}

__global__ void scan_tops(int* __restrict__ bsum, int nb, int* __restrict__ off, int n) {
    int lane = threadIdx.x & 63;
    int carry = 0;
    for (int base = 0; base < nb; base += 64) {
        int i = base + lane;
        int orig = (i < nb) ? bsum[i] : 0;
        int v = orig;
        #pragma unroll
        for (int d = 1; d < 64; d <<= 1) {
            int t = __shfl_up(v, d);
            if (lane >= d) v += t;
        }
        if (i < nb) bsum[i] = carry + v - orig;
        carry += __shfl(v, 63);
    }
    if (lane == 0) off[n] = carry;
}

__global__ void add_offsets(int* __restrict__ off, const int* __restrict__ bsum, int n) {
    int i = blockIdx.x * blockDim.x + threadIdx.x;
    if (i < n) off[i] += bsum[i >> 8];
}

__global__ void placement(const int* __restrict__ src, const int* __restrict__ dst,
                          const int* __restrict__ rank, const int* __restrict__ off,
                          int* __restrict__ csr, int E) {
    int i = blockIdx.x * blockDim.x + threadIdx.x;
    int b = i * 4;
    if (b + 3 < E) {
        int4 s = ((const int4*)src)[i];
        int4 d = ((const int4*)dst)[i];
        int4 r = ((const int4*)rank)[i];
        csr[off[d.x] + r.x] = s.x;
        csr[off[d.y] + r.y] = s.y;
        csr[off[d.z] + r.z] = s.z;
        csr[off[d.w] + r.w] = s.w;
    } else {
        for (int k = b; k < E; ++k) csr[off[dst[k]] + rank[k]] = src[k];
    }
}

// ---------------- bf16 helpers ----------------
__device__ inline u16 f32_to_bf16_rne(float f) {
    u32 u = __float_as_uint(f);
    u += 0x7fffu + ((u >> 16) & 1u);
    return (u16)(u >> 16);
}

__device__ inline void accum8(float* a, uint4 w) {
    a[0] += __uint_as_float(w.x << 16);
    a[1] += __uint_as_float(w.x & 0xffff0000u);
    a[2] += __uint_as_float(w.y << 16);
    a[3] += __uint_as_float(w.y & 0xffff0000u);
    a[4] += __uint_as_float(w.z << 16);
    a[5] += __uint_as_float(w.z & 0xffff0000u);
    a[6] += __uint_as_float(w.w << 16);
    a[7] += __uint_as_float(w.w & 0xffff0000u);
}

__device__ inline float dot16(const float4* __restrict__ w, const float4* v) {
    float acc = 0.0f;
    #pragma unroll
    for (int k = 0; k < 16; ++k) {
        float4 a = w[k], b = v[k];
        acc += a.x * b.x + a.y * b.y + a.z * b.z + a.w * b.w;
    }
    return acc;
}

__device__ inline float dot10(const float4* __restrict__ w, const float4* v) {
    float acc = 0.0f;
    #pragma unroll
    for (int k = 0; k < 10; ++k) {
        float4 a = w[k], b = v[k];
        acc += a.x * b.x + a.y * b.y + a.z * b.z + a.w * b.w;
    }
    return acc;
}

// ---------------- pre1: xl = bf16(x@W1l^T), xr = x@W1r^T + b1 ----------------
// Thread = node. x row in VGPRs; weight rows are wave-uniform -> scalar loads.
__global__ void pre1(const float* __restrict__ x, const float* __restrict__ W1l,
                     const float* __restrict__ W1r, const float* __restrict__ b1,
                     u32* __restrict__ xl, float* __restrict__ xr, int n) {
    int node = blockIdx.x * blockDim.x + threadIdx.x;
    if (node >= n) return;
    float4 xv[16];
    const float4* xp = (const float4*)(x + (size_t)node * D_IN);
    #pragma unroll
    for (int k = 0; k < 16; ++k) xv[k] = xp[k];
    u32*   outl = xl + (size_t)node * (D_H / 2);
    float* outr = xr + (size_t)node * D_H;
    for (int o = 0; o < D_H; o += 2) {
        float al0 = dot16((const float4*)(W1l + o * D_IN), xv);
        float al1 = dot16((const float4*)(W1l + (o + 1) * D_IN), xv);
        float ar0 = dot16((const float4*)(W1r + o * D_IN), xv);
        float ar1 = dot16((const float4*)(W1r + (o + 1) * D_IN), xv);
        outl[o >> 1] = (u32)f32_to_bf16_rne(al0) | ((u32)f32_to_bf16_rne(al1) << 16);
        float2 r2;
        r2.x = ar0 + b1[o];
        r2.y = ar1 + b1[o + 1];
        *(float2*)(outr + o) = r2;
    }
}

// ---------------- Layer 1: h = relu(mean_gather(xl) + xr), in-place on xr ----
__global__ void gather_node1(const u32* __restrict__ xlp,
                             const int* __restrict__ off,
                             const int* __restrict__ csr,
                             float* __restrict__ hbuf,  // xr in, h out (n x 40)
                             int n) {
    __shared__ __align__(16) float part[4][12][D_H];
    int local = threadIdx.x >> 6;
    int lane  = threadIdx.x & 63;
    int node  = blockIdx.x * 4 + local;
    int g = lane / 5;
    int t = lane - g * 5;
    int deg = 0;
    const uint4* rows = (const uint4*)xlp;   // 5 uint4 per row
    if (node < n) {
        int o0 = off[node], o1 = off[node + 1];
        deg = o1 - o0;
        float a0[8] = {0,0,0,0,0,0,0,0};
        float a1[8] = {0,0,0,0,0,0,0,0};
        float a2[8] = {0,0,0,0,0,0,0,0};
        float a3[8] = {0,0,0,0,0,0,0,0};
        for (int base = o0; base < o1; base += 64) {
            int cnt = min(64, o1 - base);
            int idx = (base + lane < o1) ? csr[base + lane] : 0;
            if (g < 12) {
                for (int j = 0; j < cnt; j += 48) {
                    int j0 = j + g, j1 = j + 12 + g, j2 = j + 24 + g, j3 = j + 36 + g;
                    int s0 = __shfl(idx, j0 & 63);
                    int s1 = __shfl(idx, j1 & 63);
                    int s2 = __shfl(idx, j2 & 63);
                    int s3 = __shfl(idx, j3 & 63);
                    uint4 w0 = rows[(size_t)s0 * 5 + t];
                    uint4 w1 = rows[(size_t)s1 * 5 + t];
                    uint4 w2 = rows[(size_t)s2 * 5 + t];
                    uint4 w3 = rows[(size_t)s3 * 5 + t];
                    if (j0 < cnt) accum8(a0, w0);
                    if (j1 < cnt) accum8(a1, w1);
                    if (j2 < cnt) accum8(a2, w2);
                    if (j3 < cnt) accum8(a3, w3);
                }
            }
        }
        if (g < 12) {
            #pragma unroll
            for (int k = 0; k < 8; ++k) a0[k] += a1[k] + a2[k] + a3[k];
            float* p = &part[local][g][t * 8];
            ((float4*)p)[0] = make_float4(a0[0], a0[1], a0[2], a0[3]);
            ((float4*)p)[1] = make_float4(a0[4], a0[5], a0[6], a0[7]);
        }
    }
    __syncthreads();
    if (node < n && lane < D_H) {
        float inv = 1.0f / fmaxf((float)deg, 1.0f);
        float agg = 0.0f;
        #pragma unroll
        for (int gg = 0; gg < 12; ++gg) agg += part[local][gg][lane];
        size_t p = (size_t)node * D_H + lane;
        hbuf[p] = fmaxf(agg * inv + hbuf[p], 0.0f);
    }
}

// ---------------- pre2: h2 = bf16(h@W2l^T) compact; hr = h@W2r^T + b2 --------
// Thread = node; h row fully in VGPRs before in-place hr writes.
__global__ void pre2(float* __restrict__ hbuf, const float* __restrict__ W2l,
                     const float* __restrict__ W2r, const float* __restrict__ b2,
                     u32* __restrict__ h2, int n) {
    int node = blockIdx.x * blockDim.x + threadIdx.x;
    if (node >= n) return;
    float4 hv[10];
    const float4* hp = (const float4*)(hbuf + (size_t)node * D_H);
    #pragma unroll
    for (int k = 0; k < 10; ++k) hv[k] = hp[k];
    u32*   outl = h2 + (size_t)node * (D_OUT / 2);
    float* outr = hbuf + (size_t)node * D_H;   // in-place, first 24 floats
    for (int o = 0; o < D_OUT; o += 2) {
        float al0 = dot10((const float4*)(W2l + o * D_H), hv);
        float al1 = dot10((const float4*)(W2l + (o + 1) * D_H), hv);
        float ar0 = dot10((const float4*)(W2r + o * D_H), hv);
        float ar1 = dot10((const float4*)(W2r + (o + 1) * D_H), hv);
        outl[o >> 1] = (u32)f32_to_bf16_rne(al0) | ((u32)f32_to_bf16_rne(al1) << 16);
        float2 r2;
        r2.x = ar0 + b2[o];
        r2.y = ar1 + b2[o + 1];
        *(float2*)(outr + o) = r2;
    }
}

// ---------------- Layer 2: out = log_softmax(mean_gather(h2) + hr) -----------
__global__ void gather_node2(const u32* __restrict__ h2p,
                             const int* __restrict__ off,
                             const int* __restrict__ csr,
                             const float* __restrict__ hbuf,  // hr rows (stride 40)
                             float* __restrict__ out, int n) {
    __shared__ __align__(16) float part[4][21][D_OUT];
    __shared__ float os[4][D_OUT];
    int local = threadIdx.x >> 6;
    int lane  = threadIdx.x & 63;
    int node  = blockIdx.x * 4 + local;
    int g = lane / 3;
    int t = lane - g * 3;
    int deg = 0;
    const uint4* rows = (const uint4*)h2p;   // 3 uint4 per row
    if (node < n) {
        int o0 = off[node], o1 = off[node + 1];
        deg = o1 - o0;
        float a0[8] = {0,0,0,0,0,0,0,0};
        float a1[8] = {0,0,0,0,0,0,0,0};
        for (int base = o0; base < o1; base += 64) {
            int cnt = min(64, o1 - base);
            int idx = (base + lane < o1) ? csr[base + lane] : 0;
            if (g < 21) {
                for (int j = 0; j < cnt; j += 42) {
                    int j0 = j + g, j1 = j + 21 + g;
                    int s0 = __shfl(idx, j0 & 63);
                    int s1 = __shfl(idx, j1 & 63);
                    uint4 w0 = rows[(size_t)s0 * 3 + t];
                    uint4 w1 = rows[(size_t)s1 * 3 + t];
                    if (j0 < cnt) accum8(a0, w0);
                    if (j1 < cnt) accum8(a1, w1);
                }
            }
        }
        if (g < 21) {
            #pragma unroll
            for (int k = 0; k < 8; ++k) a0[k] += a1[k];
            float* p = &part[local][g][t * 8];
            ((float4*)p)[0] = make_float4(a0[0], a0[1], a0[2], a0[3]);
            ((float4*)p)[1] = make_float4(a0[4], a0[5], a0[6], a0[7]);
        }
    }
    __syncthreads();
    if (node < n && lane < D_OUT) {
        float inv = 1.0f / fmaxf((float)deg, 1.0f);
        float agg = 0.0f;
        #pragma unroll
        for (int gg = 0; gg < 21; ++gg) agg += part[local][gg][lane];
        os[local][lane] = agg * inv + hbuf[(size_t)node * D_H + lane];
    }
    __syncthreads();
    if (node < n && lane < D_OUT) {
        float m = -INFINITY;
        #pragma unroll
        for (int k = 0; k < D_OUT; ++k) m = fmaxf(m, os[local][k]);
        float se = 0.0f;
        #pragma unroll
        for (int k = 0; k < D_OUT; ++k) se += expf(os[local][k] - m);
        out[(size_t)node * D_OUT + lane] = os[local][lane] - m - logf(se);
    }
}

extern "C" void kernel_launch(void* const* d_in, const int* in_sizes, int n_in,
                              void* d_out, int out_size, void* d_ws, size_t ws_size,
                              hipStream_t stream) {
    const float* x   = (const float*)d_in[0];
    const int*   ei  = (const int*)d_in[1];
    const float* W1l = (const float*)d_in[2];
    const float* b1  = (const float*)d_in[3];
    const float* W1r = (const float*)d_in[4];
    const float* W2l = (const float*)d_in[5];
    const float* b2  = (const float*)d_in[6];
    const float* W2r = (const float*)d_in[7];
    float* out = (float*)d_out;

    const int n = in_sizes[0] / D_IN;      // 100000
    const int E = in_sizes[1] / 2;         // 3200000
    const int* src = ei;
    const int* dst = ei + E;
    const int nb = (n + 255) / 256;

    // Workspace (~37.6 MB):
    //  buf0: n*40 f32 = 16 MB  — lifetimes: rank -> xr -> h -> hr (in-place)
    //  xl  : n*40 bf16 = 8 MB  — lifetimes: xl -> h2 (compact n*24 bf16)
    //  off/deg/bsum, csr (12.8 MB)
    char* ws = (char*)d_ws;
    float* buf0 = (float*)ws;
    int*   rank = (int*)ws;          ws += (size_t)n * D_H * 4;
    u16*   xl   = (u16*)ws;
    u16*   h2   = (u16*)ws;          ws += (size_t)n * D_H * 2;
    int*   off  = (int*)ws;          ws += (((size_t)(n + 1) * 4 + 15) & ~15ull);
    int*   deg  = (int*)ws;          ws += (size_t)n * 4;
    int*   bsum = (int*)ws;          ws += (((size_t)nb * 4 + 15) & ~15ull);
    int*   csr  = (int*)ws;

    hipMemsetAsync(deg, 0, (size_t)n * 4, stream);

    const int E4 = (E + 3) / 4;
    hist_rank<<<(E4 + 255) / 256, 256, 0, stream>>>(dst, deg, rank, E);
    scan_blocks<<<nb, 256, 0, stream>>>(deg, off, bsum, n);
    scan_tops<<<1, 64, 0, stream>>>(bsum, nb, off, n);
    add_offsets<<<(n + 255) / 256, 256, 0, stream>>>(off, bsum, n);
    placement<<<(E4 + 255) / 256, 256, 0, stream>>>(src, dst, rank, off, csr, E);

    pre1<<<(n + 255) / 256, 256, 0, stream>>>(x, W1l, W1r, b1, (u32*)xl, buf0, n);
    gather_node1<<<(n + 3) / 4, 256, 0, stream>>>((const u32*)xl, off, csr, buf0, n);
    pre2<<<(n + 255) / 256, 256, 0, stream>>>(buf0, W2l, W2r, b2, (u32*)h2, n);
    gather_node2<<<(n + 3) / 4, 256, 0, stream>>>((const u32*)h2, off, csr, buf0, out, n);
}

// Round 8
// 487.707 us; speedup vs baseline: 1.5005x; 1.0293x over previous
//
#include <hip/hip_runtime.h>
#include <math.h>

#define D_IN 64
#define D_H 40
#define D_OUT 24
#define NSHARD 8

typedef unsigned int u32;
typedef unsigned short u16;

// ---------------- CSR build (XCD-sharded histogram) ----------------
// Shard s = blockIdx&7 tracks the round-robin block->XCD dispatch so each
// shard's counters stay in one XCD's L2 (perf heuristic only — correctness
// holds for any block->shard mapping since placement recomputes the same s).
__global__ void hist_rank(const int* __restrict__ dst, int* __restrict__ deg8,
                          int* __restrict__ rank, int E, int n) {
    int i = blockIdx.x * blockDim.x + threadIdx.x;
    int* deg = deg8 + (size_t)(blockIdx.x & (NSHARD - 1)) * n;
    int b = i * 4;
    if (b + 3 < E) {
        int4 d = ((const int4*)dst)[i];
        int4 r;
        r.x = atomicAdd(&deg[d.x], 1);
        r.y = atomicAdd(&deg[d.y], 1);
        r.z = atomicAdd(&deg[d.z], 1);
        r.w = atomicAdd(&deg[d.w], 1);
        ((int4*)rank)[i] = r;
    } else {
        for (int k = b; k < E; ++k) rank[k] = atomicAdd(&deg[dst[k]], 1);
    }
}

__global__ void scan_blocks(const int* __restrict__ deg8, int* __restrict__ off,
                            int* __restrict__ bsum, int n) {
    __shared__ int s[256];
    int tx = threadIdx.x;
    int i = blockIdx.x * 256 + tx;
    int v = 0;
    if (i < n) {
        #pragma unroll
        for (int sh = 0; sh < NSHARD; ++sh) v += deg8[(size_t)sh * n + i];
    }
    s[tx] = v;
    __syncthreads();
    for (int d = 1; d < 256; d <<= 1) {
        int t = (tx >= d) ? s[tx - d] : 0;
        __syncthreads();
        s[tx] += t;
        __syncthreads();
    }
    if (i < n) off[i] = s[tx] - v;
    if (tx == 255) bsum[blockIdx.x] = s[255];
}

__global__ void scan_tops(int* __restrict__ bsum, int nb, int* __restrict__ off, int n) {
    int lane = threadIdx.x & 63;
    int carry = 0;
    for (int base = 0; base < nb; base += 64) {
        int i = base + lane;
        int orig = (i < nb) ? bsum[i] : 0;
        int v = orig;
        #pragma unroll
        for (int d = 1; d < 64; d <<= 1) {
            int t = __shfl_up(v, d);
            if (lane >= d) v += t;
        }
        if (i < nb) bsum[i] = carry + v - orig;
        carry += __shfl(v, 63);
    }
    if (lane == 0) off[n] = carry;
}

// Finalize off[i] and convert deg8 counts to shard base positions in-place:
// deg8[s][i] <- off[i] + sum_{s'<s} deg8[s'][i]
__global__ void add_offsets_sp(int* __restrict__ off, const int* __restrict__ bsum,
                               int* __restrict__ deg8, int n) {
    int i = blockIdx.x * blockDim.x + threadIdx.x;
    if (i < n) {
        int o = off[i] + bsum[i >> 8];
        off[i] = o;
        #pragma unroll
        for (int sh = 0; sh < NSHARD; ++sh) {
            int t = deg8[(size_t)sh * n + i];
            deg8[(size_t)sh * n + i] = o;
            o += t;
        }
    }
}

// Atomic-free placement: pos = shard_base[dst] + rank (same shard mapping as
// hist_rank — identical grid & indexing).
__global__ void placement(const int* __restrict__ src, const int* __restrict__ dst,
                          const int* __restrict__ rank, const int* __restrict__ deg8,
                          int* __restrict__ csr, int E, int n) {
    int i = blockIdx.x * blockDim.x + threadIdx.x;
    const int* sp = deg8 + (size_t)(blockIdx.x & (NSHARD - 1)) * n;
    int b = i * 4;
    if (b + 3 < E) {
        int4 s = ((const int4*)src)[i];
        int4 d = ((const int4*)dst)[i];
        int4 r = ((const int4*)rank)[i];
        csr[sp[d.x] + r.x] = s.x;
        csr[sp[d.y] + r.y] = s.y;
        csr[sp[d.z] + r.z] = s.z;
        csr[sp[d.w] + r.w] = s.w;
    } else {
        for (int k = b; k < E; ++k) csr[sp[dst[k]] + rank[k]] = src[k];
    }
}

// ---------------- bf16 helpers ----------------
__device__ inline u16 f32_to_bf16_rne(float f) {
    u32 u = __float_as_uint(f);
    u += 0x7fffu + ((u >> 16) & 1u);
    return (u16)(u >> 16);
}

__device__ inline void accum8(float* a, uint4 w) {
    a[0] += __uint_as_float(w.x << 16);
    a[1] += __uint_as_float(w.x & 0xffff0000u);
    a[2] += __uint_as_float(w.y << 16);
    a[3] += __uint_as_float(w.y & 0xffff0000u);
    a[4] += __uint_as_float(w.z << 16);
    a[5] += __uint_as_float(w.z & 0xffff0000u);
    a[6] += __uint_as_float(w.w << 16);
    a[7] += __uint_as_float(w.w & 0xffff0000u);
}

__device__ inline float dot16(const float4* __restrict__ w, const float4* v) {
    float acc = 0.0f;
    #pragma unroll
    for (int k = 0; k < 16; ++k) {
        float4 a = w[k], b = v[k];
        acc += a.x * b.x + a.y * b.y + a.z * b.z + a.w * b.w;
    }
    return acc;
}

__device__ inline float dot10(const float4* __restrict__ w, const float4* v) {
    float acc = 0.0f;
    #pragma unroll
    for (int k = 0; k < 10; ++k) {
        float4 a = w[k], b = v[k];
        acc += a.x * b.x + a.y * b.y + a.z * b.z + a.w * b.w;
    }
    return acc;
}

// ---------------- pre1: xl = bf16(x@W1l^T), xr = x@W1r^T + b1 ----------------
__global__ void pre1(const float* __restrict__ x, const float* __restrict__ W1l,
                     const float* __restrict__ W1r, const float* __restrict__ b1,
                     u32* __restrict__ xl, float* __restrict__ xr, int n) {
    int node = blockIdx.x * blockDim.x + threadIdx.x;
    if (node >= n) return;
    float4 xv[16];
    const float4* xp = (const float4*)(x + (size_t)node * D_IN);
    #pragma unroll
    for (int k = 0; k < 16; ++k) xv[k] = xp[k];
    u32*   outl = xl + (size_t)node * (D_H / 2);
    float* outr = xr + (size_t)node * D_H;
    for (int o = 0; o < D_H; o += 2) {
        float al0 = dot16((const float4*)(W1l + o * D_IN), xv);
        float al1 = dot16((const float4*)(W1l + (o + 1) * D_IN), xv);
        float ar0 = dot16((const float4*)(W1r + o * D_IN), xv);
        float ar1 = dot16((const float4*)(W1r + (o + 1) * D_IN), xv);
        outl[o >> 1] = (u32)f32_to_bf16_rne(al0) | ((u32)f32_to_bf16_rne(al1) << 16);
        float2 r2;
        r2.x = ar0 + b1[o];
        r2.y = ar1 + b1[o + 1];
        *(float2*)(outr + o) = r2;
    }
}

// ---------------- Layer 1: h = relu(mean_gather(xl) + xr), in-place on xr ----
__global__ void gather_node1(const u32* __restrict__ xlp,
                             const int* __restrict__ off,
                             const int* __restrict__ csr,
                             float* __restrict__ hbuf,  // xr in, h out (n x 40)
                             int n) {
    __shared__ __align__(16) float part[4][12][D_H];
    int local = threadIdx.x >> 6;
    int lane  = threadIdx.x & 63;
    int node  = blockIdx.x * 4 + local;
    int g = lane / 5;
    int t = lane - g * 5;
    int deg = 0;
    const uint4* rows = (const uint4*)xlp;   // 5 uint4 per row
    if (node < n) {
        int o0 = off[node], o1 = off[node + 1];
        deg = o1 - o0;
        float a0[8] = {0,0,0,0,0,0,0,0};
        float a1[8] = {0,0,0,0,0,0,0,0};
        float a2[8] = {0,0,0,0,0,0,0,0};
        float a3[8] = {0,0,0,0,0,0,0,0};
        for (int base = o0; base < o1; base += 64) {
            int cnt = min(64, o1 - base);
            int idx = (base + lane < o1) ? csr[base + lane] : 0;
            if (g < 12) {
                for (int j = 0; j < cnt; j += 48) {
                    int j0 = j + g, j1 = j + 12 + g, j2 = j + 24 + g, j3 = j + 36 + g;
                    int s0 = __shfl(idx, j0 & 63);
                    int s1 = __shfl(idx, j1 & 63);
                    int s2 = __shfl(idx, j2 & 63);
                    int s3 = __shfl(idx, j3 & 63);
                    uint4 w0 = rows[(size_t)s0 * 5 + t];
                    uint4 w1 = rows[(size_t)s1 * 5 + t];
                    uint4 w2 = rows[(size_t)s2 * 5 + t];
                    uint4 w3 = rows[(size_t)s3 * 5 + t];
                    if (j0 < cnt) accum8(a0, w0);
                    if (j1 < cnt) accum8(a1, w1);
                    if (j2 < cnt) accum8(a2, w2);
                    if (j3 < cnt) accum8(a3, w3);
                }
            }
        }
        if (g < 12) {
            #pragma unroll
            for (int k = 0; k < 8; ++k) a0[k] += a1[k] + a2[k] + a3[k];
            float* p = &part[local][g][t * 8];
            ((float4*)p)[0] = make_float4(a0[0], a0[1], a0[2], a0[3]);
            ((float4*)p)[1] = make_float4(a0[4], a0[5], a0[6], a0[7]);
        }
    }
    __syncthreads();
    if (node < n && lane < D_H) {
        float inv = 1.0f / fmaxf((float)deg, 1.0f);
        float agg = 0.0f;
        #pragma unroll
        for (int gg = 0; gg < 12; ++gg) agg += part[local][gg][lane];
        size_t p = (size_t)node * D_H + lane;
        hbuf[p] = fmaxf(agg * inv + hbuf[p], 0.0f);
    }
}

// ---------------- pre2: h2 = bf16(h@W2l^T) compact; hr = h@W2r^T + b2 --------
__global__ void pre2(float* __restrict__ hbuf, const float* __restrict__ W2l,
                     const float* __restrict__ W2r, const float* __restrict__ b2,
                     u32* __restrict__ h2, int n) {
    int node = blockIdx.x * blockDim.x + threadIdx.x;
    if (node >= n) return;
    float4 hv[10];
    const float4* hp = (const float4*)(hbuf + (size_t)node * D_H);
    #pragma unroll
    for (int k = 0; k < 10; ++k) hv[k] = hp[k];
    u32*   outl = h2 + (size_t)node * (D_OUT / 2);
    float* outr = hbuf + (size_t)node * D_H;   // in-place, first 24 floats
    for (int o = 0; o < D_OUT; o += 2) {
        float al0 = dot10((const float4*)(W2l + o * D_H), hv);
        float al1 = dot10((const float4*)(W2l + (o + 1) * D_H), hv);
        float ar0 = dot10((const float4*)(W2r + o * D_H), hv);
        float ar1 = dot10((const float4*)(W2r + (o + 1) * D_H), hv);
        outl[o >> 1] = (u32)f32_to_bf16_rne(al0) | ((u32)f32_to_bf16_rne(al1) << 16);
        float2 r2;
        r2.x = ar0 + b2[o];
        r2.y = ar1 + b2[o + 1];
        *(float2*)(outr + o) = r2;
    }
}

// ---------------- Layer 2: out = log_softmax(mean_gather(h2) + hr) -----------
__global__ void gather_node2(const u32* __restrict__ h2p,
                             const int* __restrict__ off,
                             const int* __restrict__ csr,
                             const float* __restrict__ hbuf,  // hr rows (stride 40)
                             float* __restrict__ out, int n) {
    __shared__ __align__(16) float part[4][21][D_OUT];
    __shared__ float os[4][D_OUT];
    int local = threadIdx.x >> 6;
    int lane  = threadIdx.x & 63;
    int node  = blockIdx.x * 4 + local;
    int g = lane / 3;
    int t = lane - g * 3;
    int deg = 0;
    const uint4* rows = (const uint4*)h2p;   // 3 uint4 per row
    if (node < n) {
        int o0 = off[node], o1 = off[node + 1];
        deg = o1 - o0;
        float a0[8] = {0,0,0,0,0,0,0,0};
        float a1[8] = {0,0,0,0,0,0,0,0};
        for (int base = o0; base < o1; base += 64) {
            int cnt = min(64, o1 - base);
            int idx = (base + lane < o1) ? csr[base + lane] : 0;
            if (g < 21) {
                for (int j = 0; j < cnt; j += 42) {
                    int j0 = j + g, j1 = j + 21 + g;
                    int s0 = __shfl(idx, j0 & 63);
                    int s1 = __shfl(idx, j1 & 63);
                    uint4 w0 = rows[(size_t)s0 * 3 + t];
                    uint4 w1 = rows[(size_t)s1 * 3 + t];
                    if (j0 < cnt) accum8(a0, w0);
                    if (j1 < cnt) accum8(a1, w1);
                }
            }
        }
        if (g < 21) {
            #pragma unroll
            for (int k = 0; k < 8; ++k) a0[k] += a1[k];
            float* p = &part[local][g][t * 8];
            ((float4*)p)[0] = make_float4(a0[0], a0[1], a0[2], a0[3]);
            ((float4*)p)[1] = make_float4(a0[4], a0[5], a0[6], a0[7]);
        }
    }
    __syncthreads();
    if (node < n && lane < D_OUT) {
        float inv = 1.0f / fmaxf((float)deg, 1.0f);
        float agg = 0.0f;
        #pragma unroll
        for (int gg = 0; gg < 21; ++gg) agg += part[local][gg][lane];
        os[local][lane] = agg * inv + hbuf[(size_t)node * D_H + lane];
    }
    __syncthreads();
    if (node < n && lane < D_OUT) {
        float m = -INFINITY;
        #pragma unroll
        for (int k = 0; k < D_OUT; ++k) m = fmaxf(m, os[local][k]);
        float se = 0.0f;
        #pragma unroll
        for (int k = 0; k < D_OUT; ++k) se += expf(os[local][k] - m);
        out[(size_t)node * D_OUT + lane] = os[local][lane] - m - logf(se);
    }
}

extern "C" void kernel_launch(void* const* d_in, const int* in_sizes, int n_in,
                              void* d_out, int out_size, void* d_ws, size_t ws_size,
                              hipStream_t stream) {
    const float* x   = (const float*)d_in[0];
    const int*   ei  = (const int*)d_in[1];
    const float* W1l = (const float*)d_in[2];
    const float* b1  = (const float*)d_in[3];
    const float* W1r = (const float*)d_in[4];
    const float* W2l = (const float*)d_in[5];
    const float* b2  = (const float*)d_in[6];
    const float* W2r = (const float*)d_in[7];
    float* out = (float*)d_out;

    const int n = in_sizes[0] / D_IN;      // 100000
    const int E = in_sizes[1] / 2;         // 3200000
    const int* src = ei;
    const int* dst = ei + E;
    const int nb = (n + 255) / 256;

    // Workspace (~40.4 MB):
    //  buf0: n*40 f32 = 16 MB  — lifetimes: rank -> xr -> h -> hr (in-place)
    //  xl  : n*40 bf16 = 8 MB  — lifetimes: xl -> h2 (compact n*24 bf16)
    //  off : (n+1) i32
    //  deg8: 8*n i32 = 3.2 MB  — counts, then shard base positions
    //  bsum: nb i32
    //  csr : E i32 = 12.8 MB
    char* ws = (char*)d_ws;
    float* buf0 = (float*)ws;
    int*   rank = (int*)ws;          ws += (size_t)n * D_H * 4;
    u16*   xl   = (u16*)ws;
    u16*   h2   = (u16*)ws;          ws += (size_t)n * D_H * 2;
    int*   off  = (int*)ws;          ws += (((size_t)(n + 1) * 4 + 15) & ~15ull);
    int*   deg8 = (int*)ws;          ws += (size_t)NSHARD * n * 4;
    int*   bsum = (int*)ws;          ws += (((size_t)nb * 4 + 15) & ~15ull);
    int*   csr  = (int*)ws;

    hipMemsetAsync(deg8, 0, (size_t)NSHARD * n * 4, stream);

    const int E4 = (E + 3) / 4;
    hist_rank<<<(E4 + 255) / 256, 256, 0, stream>>>(dst, deg8, rank, E, n);
    scan_blocks<<<nb, 256, 0, stream>>>(deg8, off, bsum, n);
    scan_tops<<<1, 64, 0, stream>>>(bsum, nb, off, n);
    add_offsets_sp<<<(n + 255) / 256, 256, 0, stream>>>(off, bsum, deg8, n);
    placement<<<(E4 + 255) / 256, 256, 0, stream>>>(src, dst, rank, deg8, csr, E, n);

    pre1<<<(n + 255) / 256, 256, 0, stream>>>(x, W1l, W1r, b1, (u32*)xl, buf0, n);
    gather_node1<<<(n + 3) / 4, 256, 0, stream>>>((const u32*)xl, off, csr, buf0, n);
    pre2<<<(n + 255) / 256, 256, 0, stream>>>(buf0, W2l, W2r, b2, (u32*)h2, n);
    gather_node2<<<(n + 3) / 4, 256, 0, stream>>>((const u32*)h2, off, csr, buf0, out, n);
}

// Round 9
// 384.882 us; speedup vs baseline: 1.9013x; 1.2672x over previous
//
#include <hip/hip_runtime.h>
#include <math.h>

#define D_IN 64
#define D_H 40
#define D_OUT 24
#define S_BITS 8
#define S_NODES 256      // nodes per bucket
#define CH 8192          // edges per passA/passB block
#define BMAX 512         // max buckets (n <= 131072)

typedef unsigned int u32;
typedef unsigned short u16;

// ---------------- CSR build: atomic-free LDS multisplit ----------------
// passA: per-block histogram of dst buckets (bucket = dst >> 8).
__global__ void passA(const int* __restrict__ dst, int* __restrict__ G,
                      int E, int B) {
    __shared__ int hist[BMAX];
    int tx = threadIdx.x;
    for (int i = tx; i < B; i += 256) hist[i] = 0;
    __syncthreads();
    int e0 = blockIdx.x * CH;
    int e1 = min(e0 + CH, E);
    for (int e = e0 + tx; e < e1; e += 256)
        atomicAdd(&hist[dst[e] >> S_BITS], 1);      // LDS atomic
    __syncthreads();
    for (int i = tx; i < B; i += 256) G[(size_t)blockIdx.x * B + i] = hist[i];
}

// colscan: for bucket b, exclusive-scan G[i][b] over blocks i; total -> bktTotal.
__global__ void colscan(int* __restrict__ G, int* __restrict__ bktTotal,
                        int NB1, int B) {
    int b = blockIdx.x;
    int lane = threadIdx.x;      // 64 threads
    int carry = 0;
    for (int base = 0; base < NB1; base += 64) {
        int i = base + lane;
        int orig = (i < NB1) ? G[(size_t)i * B + b] : 0;
        int v = orig;
        #pragma unroll
        for (int d = 1; d < 64; d <<= 1) {
            int t = __shfl_up(v, d);
            if (lane >= d) v += t;
        }
        if (i < NB1) G[(size_t)i * B + b] = carry + v - orig;   // exclusive
        carry += __shfl(v, 63);
    }
    if (lane == 0) bktTotal[b] = carry;
}

// bucketscan: exclusive scan of bucket totals -> bktStart[0..B]; off[n] = E.
__global__ void bucketscan(const int* __restrict__ bktTotal,
                           int* __restrict__ bktStart, int* __restrict__ off,
                           int B, int E, int n) {
    int lane = threadIdx.x;
    int carry = 0;
    for (int base = 0; base < B; base += 64) {
        int i = base + lane;
        int orig = (i < B) ? bktTotal[i] : 0;
        int v = orig;
        #pragma unroll
        for (int d = 1; d < 64; d <<= 1) {
            int t = __shfl_up(v, d);
            if (lane >= d) v += t;
        }
        if (i < B) bktStart[i] = carry + v - orig;
        carry += __shfl(v, 63);
    }
    if (lane == 0) { bktStart[B] = carry; off[n] = E; }
}

// passB: scatter edges into bucket-major order, packed (dstl<<24 | src).
__global__ void passB(const int* __restrict__ src, const int* __restrict__ dst,
                      const int* __restrict__ G, const int* __restrict__ bktStart,
                      u32* __restrict__ bucketed, int E, int B) {
    __shared__ int baseS[BMAX];
    __shared__ int cnt[BMAX];
    int tx = threadIdx.x;
    for (int i = tx; i < B; i += 256) {
        baseS[i] = bktStart[i] + G[(size_t)blockIdx.x * B + i];
        cnt[i] = 0;
    }
    __syncthreads();
    int e0 = blockIdx.x * CH;
    int e1 = min(e0 + CH, E);
    for (int e = e0 + tx; e < e1; e += 256) {
        int d = dst[e];
        int b = d >> S_BITS;
        int r = atomicAdd(&cnt[b], 1);               // LDS atomic
        bucketed[baseS[b] + r] = ((u32)(d & (S_NODES - 1)) << 24) | (u32)src[e];
    }
}

// bucket_csr: one block per bucket. Count 256 local nodes, LDS scan -> off,
// then rank+place into final CSR. No global scan, no global atomics.
__global__ void bucket_csr(const u32* __restrict__ bucketed,
                           const int* __restrict__ bktStart,
                           int* __restrict__ off, int* __restrict__ csr,
                           int n) {
    __shared__ int degl[S_NODES];
    __shared__ int offl[S_NODES + 1];
    __shared__ int cntl[S_NODES];
    int b  = blockIdx.x;
    int tx = threadIdx.x;        // 256
    int bs = bktStart[b], be = bktStart[b + 1];
    degl[tx] = 0;
    cntl[tx] = 0;
    __syncthreads();
    for (int e = bs + tx; e < be; e += 256)
        atomicAdd(&degl[bucketed[e] >> 24], 1);      // LDS atomic
    __syncthreads();
    int v = degl[tx];
    offl[tx] = v;
    __syncthreads();
    for (int d = 1; d < 256; d <<= 1) {              // Hillis-Steele inclusive
        int t = (tx >= d) ? offl[tx - d] : 0;
        __syncthreads();
        offl[tx] += t;
        __syncthreads();
    }
    int excl = offl[tx] - v;
    __syncthreads();
    offl[tx] = excl;
    if (tx == 255) offl[256] = excl + v;
    __syncthreads();
    int node = b * S_NODES + tx;
    if (node <= n) off[node] = bs + offl[tx];
    for (int e = bs + tx; e < be; e += 256) {
        u32 w = bucketed[e];
        int dl = w >> 24;
        int r = atomicAdd(&cntl[dl], 1);             // LDS atomic
        csr[bs + offl[dl] + r] = (int)(w & 0xFFFFFFu);
    }
}

// ---------------- bf16 helpers ----------------
__device__ inline u16 f32_to_bf16_rne(float f) {
    u32 u = __float_as_uint(f);
    u += 0x7fffu + ((u >> 16) & 1u);
    return (u16)(u >> 16);
}

__device__ inline void accum8(float* a, uint4 w) {
    a[0] += __uint_as_float(w.x << 16);
    a[1] += __uint_as_float(w.x & 0xffff0000u);
    a[2] += __uint_as_float(w.y << 16);
    a[3] += __uint_as_float(w.y & 0xffff0000u);
    a[4] += __uint_as_float(w.z << 16);
    a[5] += __uint_as_float(w.z & 0xffff0000u);
    a[6] += __uint_as_float(w.w << 16);
    a[7] += __uint_as_float(w.w & 0xffff0000u);
}

__device__ inline float dot16(const float4* __restrict__ w, const float4* v) {
    float acc = 0.0f;
    #pragma unroll
    for (int k = 0; k < 16; ++k) {
        float4 a = w[k], b = v[k];
        acc += a.x * b.x + a.y * b.y + a.z * b.z + a.w * b.w;
    }
    return acc;
}

__device__ inline float dot10(const float4* __restrict__ w, const float4* v) {
    float acc = 0.0f;
    #pragma unroll
    for (int k = 0; k < 10; ++k) {
        float4 a = w[k], b = v[k];
        acc += a.x * b.x + a.y * b.y + a.z * b.z + a.w * b.w;
    }
    return acc;
}

// ---------------- pre1: xl = bf16(x@W1l^T), xr = x@W1r^T + b1 ----------------
__global__ void pre1(const float* __restrict__ x, const float* __restrict__ W1l,
                     const float* __restrict__ W1r, const float* __restrict__ b1,
                     u32* __restrict__ xl, float* __restrict__ xr, int n) {
    int node = blockIdx.x * blockDim.x + threadIdx.x;
    if (node >= n) return;
    float4 xv[16];
    const float4* xp = (const float4*)(x + (size_t)node * D_IN);
    #pragma unroll
    for (int k = 0; k < 16; ++k) xv[k] = xp[k];
    u32*   outl = xl + (size_t)node * (D_H / 2);
    float* outr = xr + (size_t)node * D_H;
    for (int o = 0; o < D_H; o += 2) {
        float al0 = dot16((const float4*)(W1l + o * D_IN), xv);
        float al1 = dot16((const float4*)(W1l + (o + 1) * D_IN), xv);
        float ar0 = dot16((const float4*)(W1r + o * D_IN), xv);
        float ar1 = dot16((const float4*)(W1r + (o + 1) * D_IN), xv);
        outl[o >> 1] = (u32)f32_to_bf16_rne(al0) | ((u32)f32_to_bf16_rne(al1) << 16);
        float2 r2;
        r2.x = ar0 + b1[o];
        r2.y = ar1 + b1[o + 1];
        *(float2*)(outr + o) = r2;
    }
}

// ---------------- Layer 1: h = relu(mean_gather(xl) + xr), in-place on xr ----
__global__ void gather_node1(const u32* __restrict__ xlp,
                             const int* __restrict__ off,
                             const int* __restrict__ csr,
                             float* __restrict__ hbuf,  // xr in, h out (n x 40)
                             int n) {
    __shared__ __align__(16) float part[4][12][D_H];
    int local = threadIdx.x >> 6;
    int lane  = threadIdx.x & 63;
    int node  = blockIdx.x * 4 + local;
    int g = lane / 5;
    int t = lane - g * 5;
    int deg = 0;
    const uint4* rows = (const uint4*)xlp;   // 5 uint4 per row
    if (node < n) {
        int o0 = off[node], o1 = off[node + 1];
        deg = o1 - o0;
        float a0[8] = {0,0,0,0,0,0,0,0};
        float a1[8] = {0,0,0,0,0,0,0,0};
        float a2[8] = {0,0,0,0,0,0,0,0};
        float a3[8] = {0,0,0,0,0,0,0,0};
        for (int base = o0; base < o1; base += 64) {
            int cnt = min(64, o1 - base);
            int idx = (base + lane < o1) ? csr[base + lane] : 0;
            if (g < 12) {
                for (int j = 0; j < cnt; j += 48) {
                    int j0 = j + g, j1 = j + 12 + g, j2 = j + 24 + g, j3 = j + 36 + g;
                    int s0 = __shfl(idx, j0 & 63);
                    int s1 = __shfl(idx, j1 & 63);
                    int s2 = __shfl(idx, j2 & 63);
                    int s3 = __shfl(idx, j3 & 63);
                    uint4 w0 = rows[(size_t)s0 * 5 + t];
                    uint4 w1 = rows[(size_t)s1 * 5 + t];
                    uint4 w2 = rows[(size_t)s2 * 5 + t];
                    uint4 w3 = rows[(size_t)s3 * 5 + t];
                    if (j0 < cnt) accum8(a0, w0);
                    if (j1 < cnt) accum8(a1, w1);
                    if (j2 < cnt) accum8(a2, w2);
                    if (j3 < cnt) accum8(a3, w3);
                }
            }
        }
        if (g < 12) {
            #pragma unroll
            for (int k = 0; k < 8; ++k) a0[k] += a1[k] + a2[k] + a3[k];
            float* p = &part[local][g][t * 8];
            ((float4*)p)[0] = make_float4(a0[0], a0[1], a0[2], a0[3]);
            ((float4*)p)[1] = make_float4(a0[4], a0[5], a0[6], a0[7]);
        }
    }
    __syncthreads();
    if (node < n && lane < D_H) {
        float inv = 1.0f / fmaxf((float)deg, 1.0f);
        float agg = 0.0f;
        #pragma unroll
        for (int gg = 0; gg < 12; ++gg) agg += part[local][gg][lane];
        size_t p = (size_t)node * D_H + lane;
        hbuf[p] = fmaxf(agg * inv + hbuf[p], 0.0f);
    }
}

// ---------------- pre2: h2 = bf16(h@W2l^T) compact; hr = h@W2r^T + b2 --------
__global__ void pre2(float* __restrict__ hbuf, const float* __restrict__ W2l,
                     const float* __restrict__ W2r, const float* __restrict__ b2,
                     u32* __restrict__ h2, int n) {
    int node = blockIdx.x * blockDim.x + threadIdx.x;
    if (node >= n) return;
    float4 hv[10];
    const float4* hp = (const float4*)(hbuf + (size_t)node * D_H);
    #pragma unroll
    for (int k = 0; k < 10; ++k) hv[k] = hp[k];
    u32*   outl = h2 + (size_t)node * (D_OUT / 2);
    float* outr = hbuf + (size_t)node * D_H;   // in-place, first 24 floats
    for (int o = 0; o < D_OUT; o += 2) {
        float al0 = dot10((const float4*)(W2l + o * D_H), hv);
        float al1 = dot10((const float4*)(W2l + (o + 1) * D_H), hv);
        float ar0 = dot10((const float4*)(W2r + o * D_H), hv);
        float ar1 = dot10((const float4*)(W2r + (o + 1) * D_H), hv);
        outl[o >> 1] = (u32)f32_to_bf16_rne(al0) | ((u32)f32_to_bf16_rne(al1) << 16);
        float2 r2;
        r2.x = ar0 + b2[o];
        r2.y = ar1 + b2[o + 1];
        *(float2*)(outr + o) = r2;
    }
}

// ---------------- Layer 2: out = log_softmax(mean_gather(h2) + hr) -----------
__global__ void gather_node2(const u32* __restrict__ h2p,
                             const int* __restrict__ off,
                             const int* __restrict__ csr,
                             const float* __restrict__ hbuf,  // hr rows (stride 40)
                             float* __restrict__ out, int n) {
    __shared__ __align__(16) float part[4][21][D_OUT];
    __shared__ float os[4][D_OUT];
    int local = threadIdx.x >> 6;
    int lane  = threadIdx.x & 63;
    int node  = blockIdx.x * 4 + local;
    int g = lane / 3;
    int t = lane - g * 3;
    int deg = 0;
    const uint4* rows = (const uint4*)h2p;   // 3 uint4 per row
    if (node < n) {
        int o0 = off[node], o1 = off[node + 1];
        deg = o1 - o0;
        float a0[8] = {0,0,0,0,0,0,0,0};
        float a1[8] = {0,0,0,0,0,0,0,0};
        for (int base = o0; base < o1; base += 64) {
            int cnt = min(64, o1 - base);
            int idx = (base + lane < o1) ? csr[base + lane] : 0;
            if (g < 21) {
                for (int j = 0; j < cnt; j += 42) {
                    int j0 = j + g, j1 = j + 21 + g;
                    int s0 = __shfl(idx, j0 & 63);
                    int s1 = __shfl(idx, j1 & 63);
                    uint4 w0 = rows[(size_t)s0 * 3 + t];
                    uint4 w1 = rows[(size_t)s1 * 3 + t];
                    if (j0 < cnt) accum8(a0, w0);
                    if (j1 < cnt) accum8(a1, w1);
                }
            }
        }
        if (g < 21) {
            #pragma unroll
            for (int k = 0; k < 8; ++k) a0[k] += a1[k];
            float* p = &part[local][g][t * 8];
            ((float4*)p)[0] = make_float4(a0[0], a0[1], a0[2], a0[3]);
            ((float4*)p)[1] = make_float4(a0[4], a0[5], a0[6], a0[7]);
        }
    }
    __syncthreads();
    if (node < n && lane < D_OUT) {
        float inv = 1.0f / fmaxf((float)deg, 1.0f);
        float agg = 0.0f;
        #pragma unroll
        for (int gg = 0; gg < 21; ++gg) agg += part[local][gg][lane];
        os[local][lane] = agg * inv + hbuf[(size_t)node * D_H + lane];
    }
    __syncthreads();
    if (node < n && lane < D_OUT) {
        float m = -INFINITY;
        #pragma unroll
        for (int k = 0; k < D_OUT; ++k) m = fmaxf(m, os[local][k]);
        float se = 0.0f;
        #pragma unroll
        for (int k = 0; k < D_OUT; ++k) se += expf(os[local][k] - m);
        out[(size_t)node * D_OUT + lane] = os[local][lane] - m - logf(se);
    }
}

extern "C" void kernel_launch(void* const* d_in, const int* in_sizes, int n_in,
                              void* d_out, int out_size, void* d_ws, size_t ws_size,
                              hipStream_t stream) {
    const float* x   = (const float*)d_in[0];
    const int*   ei  = (const int*)d_in[1];
    const float* W1l = (const float*)d_in[2];
    const float* b1  = (const float*)d_in[3];
    const float* W1r = (const float*)d_in[4];
    const float* W2l = (const float*)d_in[5];
    const float* b2  = (const float*)d_in[6];
    const float* W2r = (const float*)d_in[7];
    float* out = (float*)d_out;

    const int n = in_sizes[0] / D_IN;      // 100000
    const int E = in_sizes[1] / 2;         // 3200000
    const int* src = ei;
    const int* dst = ei + E;

    const int B   = (n + S_NODES - 1) >> S_BITS;   // 391 buckets
    const int NB1 = (E + CH - 1) / CH;             // 391 edge blocks

    // Workspace (~38 MB):
    //  region0: n*40 f32 = 16 MB — bucketed (E u32, 12.8MB) then xr/h/hr (buf0)
    //  xl : n*40 bf16 = 8 MB — xl then h2 (compact n*24 bf16)
    //  off: (n+1) i32
    //  G  : NB1*B i32 ≈ 0.61 MB
    //  bktTotal: B i32 ; bktStart: (B+1) i32
    //  csr: E i32 = 12.8 MB
    char* ws = (char*)d_ws;
    float* buf0     = (float*)ws;
    u32*   bucketed = (u32*)ws;      ws += (size_t)n * D_H * 4;
    u16*   xl       = (u16*)ws;
    u16*   h2       = (u16*)ws;      ws += (size_t)n * D_H * 2;
    int*   off      = (int*)ws;      ws += (((size_t)(n + 1) * 4 + 15) & ~15ull);
    int*   G        = (int*)ws;      ws += (((size_t)NB1 * B * 4 + 15) & ~15ull);
    int*   bktTotal = (int*)ws;      ws += (((size_t)B * 4 + 15) & ~15ull);
    int*   bktStart = (int*)ws;      ws += (((size_t)(B + 1) * 4 + 15) & ~15ull);
    int*   csr      = (int*)ws;

    passA<<<NB1, 256, 0, stream>>>(dst, G, E, B);
    colscan<<<B, 64, 0, stream>>>(G, bktTotal, NB1, B);
    bucketscan<<<1, 64, 0, stream>>>(bktTotal, bktStart, off, B, E, n);
    passB<<<NB1, 256, 0, stream>>>(src, dst, G, bktStart, bucketed, E, B);
    bucket_csr<<<B, 256, 0, stream>>>(bucketed, bktStart, off, csr, n);

    pre1<<<(n + 255) / 256, 256, 0, stream>>>(x, W1l, W1r, b1, (u32*)xl, buf0, n);
    gather_node1<<<(n + 3) / 4, 256, 0, stream>>>((const u32*)xl, off, csr, buf0, n);
    pre2<<<(n + 255) / 256, 256, 0, stream>>>(buf0, W2l, W2r, b2, (u32*)h2, n);
    gather_node2<<<(n + 3) / 4, 256, 0, stream>>>((const u32*)h2, off, csr, buf0, out, n);
}